// Round 12
// baseline (318.529 us; speedup 1.0000x reference)
//
#include <hip/hip_runtime.h>

// Problem constants (match reference)
#define NX       512
#define NY       512
#define NCK      16
#define NCE      8
#define NCC      64                    // cksr in [0,8) => cc in [0,64)
#define STRIPW   16                    // x-columns per tile
#define NSTRIP   (NX / STRIPW)         // 32
#define NBUCKET  (NCC * NSTRIP)        // 2048
#define SEGK     64                    // segments per bucket = by0 & 63 (lane binding)
#define SEGCAP   32                    // per segment: mean 9.5, +7 sigma
#define BSTRIDE  (SEGK * SEGCAP)       // 2048 entries per bucket
#define NSEG     (NBUCKET * SEGK)      // 131072
#define NENT     ((size_t)NBUCKET * BSTRIDE)
#define TILEC    18                    // 16 real cols + 1 guard col each side
#define TILER    514                   // 512 real rows + 1 guard row each side
#define TILEN    (TILEC * TILER)       // 9252 floats = 37 KB
#define RCAP     8                     // cached entries per lane per round
#define SQRT1_2  0.70710678118654752440f
#define INV_SLICE_CAP (1.0f / 16.0f)

// ---------------------------------------------------------------------------
// R11: NO LDS ATOMICS. R10's counters (conflicts -500x, dur -12%) pinned the
// ~110us residual on ds_add_f32 itself (~0.5-1 op/cyc/CU serialized RMW unit).
// New ff_main: ONE WAVE per bucket; lane l owns y-residue l (build segments
// by by0&63). In a lockstep (i,j) step all lanes hit rows by0+j, distinct
// mod 64 => distinct cells => plain tile[idx] += w via the fast banked path:
//  - cross-lane safe: distinct rows per step
//  - cross-step safe: per-wave LDS ops complete in issue order
//  - intra-lane same-(bx0,by0) dups (~18 pairs/bucket): dup-rank pass loop
//  - y/x clamp collisions: guard rows/cols, folded after scatter (reference
//    clip semantics preserved; col-fold BEFORE row-fold for the corner)
// Build/reduce unchanged except segment key (by0&63, SEGCAP 32).
// ---------------------------------------------------------------------------

__device__ __forceinline__ float erf_fast(float x) {
    // Abramowitz-Stegun 7.1.26, branchless; |err| <= 1.5e-7
    float ax = fabsf(x);
    float t = 1.0f / (1.0f + 0.3275911f * ax);
    float y = t * (0.254829592f + t * (-0.284496736f + t * (1.421413741f +
              t * (-1.453152027f + t * 1.061405429f))));
    float r = 1.0f - y * __expf(-ax * ax);
    return copysignf(r, x);
}

__global__ __launch_bounds__(256) void ff_build(
    const float* __restrict__ pos,        // [2N] x then y
    const int*   __restrict__ ctrl,       // [F,3]
    const float* __restrict__ nsx,        // [N]
    const float* __restrict__ nsy,        // [N]
    int*  __restrict__ cnt,               // [NSEG]
    int4* __restrict__ entries,           // [NENT], [bucket][rank][residue64]
    int2* __restrict__ slots,             // [F]
    int F, int Nn)
{
    int f = blockIdx.x * blockDim.x + threadIdx.x;
    if (f >= F) return;

    float cx = pos[f]      + 0.5f * nsx[f];     // fi == f (fidx = arange)
    float cy = pos[Nn + f] + 0.5f * nsy[f];
    int bx0 = (int)floorf(cx);                  // INV_SX=1, XL=0
    int by0 = (int)floorf(cy);
    int cksr = ctrl[3 * f + 1] & (NCK - 1);     // in [0,8)
    int ce   = ctrl[3 * f + 2] & (NCE - 1);
    int cc   = cksr * NCE + ce;                 // in [0,64)

    int xlo = min(max(bx0 - 2, 0), NX - 1);     // clipped window extent
    int xhi = min(max(bx0 + 2, 0), NX - 1);
    int s_lo = xlo / STRIPW;
    int s_hi = xhi / STRIPW;                    // s_hi - s_lo in {0,1}

    int rep = by0 & (SEGK - 1);                 // y-residue = future lane

    int4 v;
    v.x = f;
    v.y = __float_as_int(cx);
    v.z = __float_as_int(cy);
    v.w = 0;

    int idx0 = -1, idx1 = -1;
    int bkt0 = cc * NSTRIP + s_lo;
    int p = atomicAdd(&cnt[bkt0 * SEGK + rep], 1);
    if (p < SEGCAP) { idx0 = bkt0 * BSTRIDE + p * SEGK + rep; entries[idx0] = v; }
    if (s_hi != s_lo) {
        int bkt1 = cc * NSTRIP + s_hi;
        int q = atomicAdd(&cnt[bkt1 * SEGK + rep], 1);
        if (q < SEGCAP) { idx1 = bkt1 * BSTRIDE + q * SEGK + rep; entries[idx1] = v; }
    }
    slots[f] = make_int2(idx0, idx1);           // coalesced
}

// One wave per bucket. Atomic-free scatter + fold + gather.
__global__ __launch_bounds__(64) void ff_main(
    const int*  __restrict__ cnt,
    const int4* __restrict__ entries,
    float* __restrict__ part)
{
    int b = blockIdx.x;
    int l = threadIdx.x;                  // 0..63 == my y-residue
    int s = b & (NSTRIP - 1);
    int x0 = s * STRIPW;
    size_t ebase = (size_t)b * BSTRIDE;
    int cseg = min(cnt[b * SEGK + l], SEGCAP);

    __shared__ float tile[TILEN];         // [col 0..17][row 0..513], guards at edges
    {
        float4* t4 = (float4*)tile;       // TILEN = 9252 = 4*2313
        for (int k = l; k < TILEN / 4; k += 64)
            t4[k] = make_float4(0.f, 0.f, 0.f, 0.f);
    }
    __syncthreads();

    // ---- scatter: rounds of RCAP cached entries per lane ----
    int r0 = 0;
    while (__any(r0 < cseg)) {
        float dx[RCAP][5], dy[RCAP][5];
        int ibx[RCAP], iby[RCAP], key[RCAP], dcnt[RCAP];
        bool val[RCAP];
#pragma unroll
        for (int e = 0; e < RCAP; ++e) {
            int r = r0 + e;
            val[e] = (r < cseg);
            key[e] = 0x100000 + e;        // unique invalid key (> any (bx<<10)|by)
            ibx[e] = 0; iby[e] = 1;
#pragma unroll
            for (int k = 0; k < 5; ++k) { dx[e][k] = 0.f; dy[e][k] = 0.f; }
            if (val[e]) {
                int4 E = entries[ebase + (size_t)r * SEGK + l];
                float cx = __int_as_float(E.y);
                float cy = __int_as_float(E.z);
                int bx0 = (int)floorf(cx);
                int by0 = (int)floorf(cy); // == l (mod 64) by construction
                float fx = cx - (float)bx0;
                float fy = cy - (float)by0;
                float Ex[6], Ey[6];
#pragma unroll
                for (int k = 0; k < 6; ++k) {
                    Ex[k] = erf_fast(((float)(k - 2) - fx) * SQRT1_2);
                    Ey[k] = erf_fast(((float)(k - 2) - fy) * SQRT1_2);
                }
                float invx = 1.0f / (Ex[5] - Ex[0]);
                float invy = 1.0f / (Ey[5] - Ey[0]);
#pragma unroll
                for (int k = 0; k < 5; ++k) {
                    dx[e][k] = (Ex[k + 1] - Ex[k]) * invx;
                    dy[e][k] = (Ey[k + 1] - Ey[k]) * invy;
                }
                ibx[e] = bx0; iby[e] = by0;
                key[e] = (bx0 << 10) | by0;
            }
        }
        // dup rank among my cached entries (same (bx0,by0) => same cells)
#pragma unroll
        for (int e = 0; e < RCAP; ++e) dcnt[e] = 0;
#pragma unroll
        for (int e = 1; e < RCAP; ++e)
#pragma unroll
            for (int a = 0; a < e; ++a)
                dcnt[e] += (key[a] == key[e]) ? 1 : 0;
        int lanemax = 0;
#pragma unroll
        for (int e = 0; e < RCAP; ++e) if (val[e]) lanemax = max(lanemax, dcnt[e]);

        // pass p handles dup-rank p (in-order LDS makes pass p+1 see pass p)
        for (int p = 0; __any(p <= lanemax); ++p) {
#pragma unroll
            for (int i = 0; i < 5; ++i) {
#pragma unroll
                for (int j = 0; j < 5; ++j) {
#pragma unroll
                    for (int e = 0; e < RCAP; ++e) {
                        bool act = val[e] && (dcnt[e] == p);
                        int rc = ibx[e] + i - 2 - x0 + 1;      // tile col incl guards
                        bool ok = act && (rc >= 0) && (rc < TILEC);
                        int rcs = min(max(rc, 0), TILEC - 1);
                        int idx = rcs * TILER + (iby[e] + j - 1); // row: by0+j-2 +1
                        if (ok) tile[idx] += dx[e][i] * dy[e][j]; // plain RMW: race-free
                    }
                }
            }
        }
        r0 += RCAP;
    }

    // ---- fold guards (reference clip semantics). Col-fold FIRST (corner!) ----
    if (s == 0) {
        for (int r = l; r < TILER; r += 64)
            tile[1 * TILER + r] += tile[0 * TILER + r];        // raw col -1 -> col 0
    } else if (s == NSTRIP - 1) {
        for (int r = l; r < TILER; r += 64)
            tile[16 * TILER + r] += tile[17 * TILER + r];      // raw col 512 -> 511
    }
    if (l < TILEC) {
        float* col = &tile[l * TILER];
        col[1]   += col[0];                                    // raw row -1 -> row 0
        col[512] += col[513];                                  // raw row 512 -> 511
    }
    __syncthreads();

    // ---- gather (reads only; unclipped in-range mask, clipped address) ----
    for (int r = 0; r < cseg; ++r) {
        int4 E = entries[ebase + (size_t)r * SEGK + l];
        float cx = __int_as_float(E.y);
        float cy = __int_as_float(E.z);
        int bx0 = (int)floorf(cx);
        int by0 = (int)floorf(cy);
        float area = 0.0f;
#pragma unroll
        for (int i = 0; i < 5; ++i) {
            int bxi = bx0 + i - 2;
            if (bxi < x0 || bxi >= x0 + STRIPW) continue;      // owned & in-range
            const float* row = &tile[(bxi - x0 + 1) * TILER];
#pragma unroll
            for (int j = 0; j < 5; ++j) {
                int byj = by0 + j - 2;
                int byc = min(max(byj, 0), NY - 1);
                float m = (byj == byc) ? 1.0f : 0.0f;
                area += row[byc + 1] * m;
            }
        }
        part[ebase + (size_t)r * SEGK + l] = area * INV_SLICE_CAP;
    }
}

// out[f] = part[idx0] + part[idx1]; zero for f >= F.
__global__ __launch_bounds__(256) void ff_reduce(
    const int2*  __restrict__ slots,
    const float* __restrict__ part,
    float* __restrict__ out, int F, int out_n)
{
    int f = blockIdx.x * blockDim.x + threadIdx.x;
    if (f >= out_n) return;
    float v = 0.0f;
    if (f < F) {
        int2 sl = slots[f];
        if (sl.x >= 0) v += part[sl.x];
        if (sl.y >= 0) v += part[sl.y];
    }
    out[f] = v;
}

extern "C" void kernel_launch(void* const* d_in, const int* in_sizes, int n_in,
                              void* d_out, int out_size, void* d_ws, size_t ws_size,
                              hipStream_t stream) {
    const float* pos  = (const float*)d_in[0];
    const int*   ctrl = (const int*)d_in[2];
    const float* nsx  = (const float*)d_in[3];
    const float* nsy  = (const float*)d_in[4];
    float* out = (float*)d_out;

    const int F  = in_sizes[1];
    const int Nn = in_sizes[3];

    // Workspace (ws >= 128 MiB known from R0):
    //   cnt     : NSEG ints   = 512 KB   (offset 0)
    //   entries : NENT int4   = 67.1 MB
    //   part    : NENT float  = 16.8 MB
    //   slots   : F int2      =  8.0 MB     total ~92.4 MB
    char* ws = (char*)d_ws;
    int*   cnt     = (int*)ws;
    int4*  entries = (int4*)(ws + 512 * 1024);
    float* part    = (float*)(ws + 512 * 1024 + NENT * sizeof(int4));
    int2*  slots   = (int2*)(ws + 512 * 1024 + NENT * sizeof(int4)
                                + NENT * sizeof(float));

    hipMemsetAsync(cnt, 0, NSEG * sizeof(int), stream);

    int threads = 256;
    int blocks = (F + threads - 1) / threads;
    ff_build<<<blocks, threads, 0, stream>>>(pos, ctrl, nsx, nsy,
                                             cnt, entries, slots, F, Nn);
    ff_main<<<NBUCKET, 64, 0, stream>>>(cnt, entries, part);
    int rblocks = (out_size + threads - 1) / threads;
    ff_reduce<<<rblocks, threads, 0, stream>>>(slots, part, out, F, out_size);
}